// Round 9
// baseline (78.180 us; speedup 1.0000x reference)
//
#include <hip/hip_runtime.h>

typedef __bf16 bf16;
typedef __attribute__((ext_vector_type(4))) __bf16 bf16x4;
typedef __attribute__((ext_vector_type(8))) __bf16 bf16x8;
typedef __attribute__((ext_vector_type(4))) float f32x4;
typedef __attribute__((ext_vector_type(16))) float f32x16;
typedef unsigned int u32;

#define MFMA16(a, b, c) __builtin_amdgcn_mfma_f32_16x16x32_bf16((a), (b), (c), 0, 0, 0)
#define MFMA32(a, b, c) __builtin_amdgcn_mfma_f32_32x32x16_bf16((a), (b), (c), 0, 0, 0)
#define LOG2E 1.4426950408889634f
#define AS1 __attribute__((address_space(1)))
#define AS3 __attribute__((address_space(3)))
#define GLL16(g, l) __builtin_amdgcn_global_load_lds((const AS1 u32*)(g), (AS3 u32*)(l), 16, 0, 0)

// KV chunk layout, per (b, kt): 40960 bytes =
//   [0,8192):     K tile [64 rows][64 o] bf16, 16B-block swizzle blk^(row&7);
//                 image row (32s + m) holds K kv-row (32s + sigma(m)),
//                 sigma(m) = m ^ (bit2(m)^bit3(m) ? 12 : 0)  (involution)
//   [8192,40960): V tile [256 c][64 q] bf16, swizzle blk^(c&7)
// Pre-swizzled in GLOBAL so attn stages a LINEAR image via global_load_lds.

// ---------------------------------------------------------------------------
// Kernel 1: fused V-convert + W prep (unchanged from R7).
// ---------------------------------------------------------------------------
__global__ __launch_bounds__(256) void vprep_kernel(const float* __restrict__ kf,
                                                    const float* __restrict__ Wq,
                                                    const float* __restrict__ Wk,
                                                    const int* __restrict__ flag,
                                                    bf16* __restrict__ KV,
                                                    bf16* __restrict__ Wbh,
                                                    bf16* __restrict__ Wbl) {
  const int bid = blockIdx.x, t = threadIdx.x;
  if (bid < 4096) {
    int i = (bid << 8) + t;  // (b, c, q8)
    int q8 = i & 127, c = (i >> 7) & 255, b = i >> 15;
    const float* src = kf + ((size_t)(((b << 8) + c)) << 10) + (q8 << 3);
    float4 f0 = *(const float4*)src;
    float4 f1 = *(const float4*)(src + 4);
    bf16x8 v;
    v[0] = (bf16)f0.x; v[1] = (bf16)f0.y; v[2] = (bf16)f0.z; v[3] = (bf16)f0.w;
    v[4] = (bf16)f1.x; v[5] = (bf16)f1.y; v[6] = (bf16)f1.z; v[7] = (bf16)f1.w;
    int kt = q8 >> 3, qb = q8 & 7;
    char* dst = (char*)KV + (size_t)((b << 4) + kt) * 40960 + 8192 + c * 128 +
                16 * (qb ^ (c & 7));
    *(bf16x8*)dst = v;
  } else {
    int bx = bid - 4096;  // 0..31
    int z = bx >> 4;
    const float* src = (z == 0) ? Wq : ((flag[0] != 0) ? Wq : Wk);
    const float sc = (z == 0) ? LOG2E : 1.0f;  // exp2-domain softmax
    int i = ((((bx & 15) << 8) + t) << 2);
    float4 vv = *(const float4*)(src + i);
    vv.x *= sc; vv.y *= sc; vv.z *= sc; vv.w *= sc;
    bf16x4 hi, lo;
    hi[0] = (bf16)vv.x; lo[0] = (bf16)(vv.x - (float)hi[0]);
    hi[1] = (bf16)vv.y; lo[1] = (bf16)(vv.y - (float)hi[1]);
    hi[2] = (bf16)vv.z; lo[2] = (bf16)(vv.z - (float)hi[2]);
    hi[3] = (bf16)vv.w; lo[3] = (bf16)(vv.w - (float)hi[3]);
    *(bf16x4*)(Wbh + (z << 14) + i) = hi;
    *(bf16x4*)(Wbl + (z << 14) + i) = lo;
  }
}

// ---------------------------------------------------------------------------
// Kernel 2: MFMA projection (R7 + sigma-permuted K store row).
// ---------------------------------------------------------------------------
__global__ __launch_bounds__(256) void proj_kernel(const float* __restrict__ qf,
                                                   const bf16* __restrict__ Wbh,
                                                   const bf16* __restrict__ Wbl,
                                                   const float* __restrict__ bq,
                                                   const float* __restrict__ bk,
                                                   const int* __restrict__ flag,
                                                   bf16* __restrict__ Qp,
                                                   bf16* __restrict__ KV) {
  const int b = blockIdx.y, z = blockIdx.z;
  const bf16* Wh = Wbh + z * 16384;
  const bf16* Wl = Wbl + z * 16384;
  const float* bias = z ? (flag[0] ? bq : bk) : bq;

  const int t = threadIdx.x;
  const int w = t >> 6, lane = t & 63;
  const int g = lane >> 4, l16 = lane & 15;
  const int wo = w >> 1, wp = w & 1;
  const int o0 = wo << 5;
  const int pbase = (blockIdx.x << 7) + (wp << 6);

  f32x4 acc[2][4];
#pragma unroll
  for (int ot = 0; ot < 2; ++ot) {
    float4 bv = *(const float4*)(bias + o0 + (ot << 4) + (g << 2));
    if (z == 0) { bv.x *= LOG2E; bv.y *= LOG2E; bv.z *= LOG2E; bv.w *= LOG2E; }
#pragma unroll
    for (int pt = 0; pt < 4; ++pt) acc[ot][pt] = (f32x4){bv.x, bv.y, bv.z, bv.w};
  }

  const float* xb = qf + ((((b << 8) + (g << 3)) << 10) + pbase + l16);
  const char* vsrc = (const char*)KV + (size_t)((b << 4) + (pbase >> 6)) * 40960 +
                     8192 + ((l16 & 7) << 1);
  const bf16* whb = Wh + ((o0 + l16) << 8) + (g << 3);
  const bf16* wlb = Wl + ((o0 + l16) << 8) + (g << 3);

  for (int kk = 0; kk < 8; ++kk) {
    bf16x8 ah[2], al[2];
#pragma unroll
    for (int ot = 0; ot < 2; ++ot) {
      ah[ot] = *(const bf16x8*)(whb + (ot << 12) + (kk << 5));
      al[ot] = *(const bf16x8*)(wlb + (ot << 12) + (kk << 5));
    }
#pragma unroll
    for (int pt = 0; pt < 4; ++pt) {
      bf16x8 xf;
      if (z == 0) {
        const float* xk = xb + (kk << 15);
        float xv[8];
#pragma unroll
        for (int j = 0; j < 8; ++j) xv[j] = xk[(j << 10) + (pt << 4)];
#pragma unroll
        for (int j = 0; j < 8; ++j) xf[j] = (bf16)xv[j];
      } else {
        const int pb3 = (pt << 1) + (l16 >> 3);
        const char* vp = vsrc + (((kk << 5) + (g << 3)) << 7);
#pragma unroll
        for (int j = 0; j < 8; ++j)
          xf[j] = *(const bf16*)(vp + (j << 7) + ((pb3 ^ j) << 4));
      }
#pragma unroll
      for (int ot = 0; ot < 2; ++ot) {
        acc[ot][pt] = MFMA16(ah[ot], xf, acc[ot][pt]);
        acc[ot][pt] = MFMA16(al[ot], xf, acc[ot][pt]);
      }
    }
  }

#pragma unroll
  for (int ot = 0; ot < 2; ++ot)
#pragma unroll
    for (int pt = 0; pt < 4; ++pt) {
      bf16x4 q4;
#pragma unroll
      for (int r = 0; r < 4; ++r) q4[r] = (bf16)acc[ot][pt][r];
      int p = pbase + (pt << 4) + l16;
      if (z == 0) {
        *(bf16x4*)(Qp + ((((b << 10) + p)) << 6) + o0 + (ot << 4) + (g << 2)) = q4;
      } else {
        int kt = p >> 6, q = p & 63;
        int x = q & 31;
        int qi = (x ^ ((((x >> 2) ^ (x >> 3)) & 1) ? 12 : 0)) | (q & 32);  // sigma
        int blk = (o0 >> 3) + (ot << 1) + (g >> 1);
        char* dst = (char*)KV + (size_t)((b << 4) + kt) * 40960 + qi * 128 +
                    16 * (blk ^ (qi & 7)) + ((g & 1) << 3);
        *(bf16x4*)dst = q4;
      }
    }
}

// ---------------------------------------------------------------------------
// Kernel 3: fused flash attention, 32x32 MFMA. grid 512 x 128 thr (2 waves).
// Wave = 32 px (px = lane&31): S^T = K.Q^T (2 tiles x 4 mfma32, sigma-permuted
// K rows -> P fully in-lane), softmax 32 vals/lane + 1 shfl, PV = 8x4 mfma32
// over all 256 channels. gll double-buffer, 1 barrier/iter. 2 blocks/CU.
// ---------------------------------------------------------------------------
__global__ __launch_bounds__(128, 1) void attn_kernel(const bf16* __restrict__ KV,
                                                      const bf16* __restrict__ Qp,
                                                      float* __restrict__ out) {
  const int bid = blockIdx.x;
  const int wkid = ((bid & 7) << 6) + (bid >> 3);  // bijective: 512 % 8 == 0
  const int b = wkid >> 4, ptile = wkid & 15;
  const int p0 = ptile << 6;
  const int t = threadIdx.x;
  const int w = t >> 6, lane = t & 63;
  const int m = lane & 31, u2 = lane >> 5;
  const int px = p0 + (w << 5) + m;  // this lane's output pixel (D col)
  const int m7 = m & 7;

  __shared__ __align__(16) unsigned char smem[2][40960];

  // Q B-frags: qa[ko][j] = Qp[px][16ko + 8u2 + j]
  const bf16* qb = Qp + (((size_t)(b << 10) + px) << 6) + (u2 << 3);
  bf16x8 qa[4];
#pragma unroll
  for (int ko = 0; ko < 4; ++ko) qa[ko] = *(const bf16x8*)(qb + (ko << 4));

  const char* chunk0 = (const char*)KV + (size_t)b * (16 * 40960);

  f32x16 acc[8];  // D[c][px]: c = 32cb + (r&3) + 8*(r>>2) + 4*u2
#pragma unroll
  for (int i = 0; i < 8; ++i)
#pragma unroll
    for (int r = 0; r < 16; ++r) acc[i][r] = 0.f;
  float m_ = -1e30f, l_ = 0.f;

  // ---- stage tile 0 (2 waves x 20 x 16B x 64 lanes = 40960) ----
  {
    const char* g = chunk0 + w * 20480 + (lane << 4);
    unsigned char* l = smem[0] + w * 20480;
#pragma unroll
    for (int op = 0; op < 20; ++op) GLL16(g + op * 1024, l + op * 1024);
  }
  asm volatile("s_waitcnt vmcnt(0)" ::: "memory");
  __syncthreads();

  int cur = 0;
  for (int kt = 0; kt < 16; ++kt) {
    if (kt < 15) {
      const char* g = chunk0 + (kt + 1) * 40960 + w * 20480 + (lane << 4);
      unsigned char* l = smem[cur ^ 1] + w * 20480;
#pragma unroll
      for (int op = 0; op < 20; ++op) GLL16(g + op * 1024, l + op * 1024);
    }
    const unsigned char* sK = smem[cur];
    const unsigned char* sV = smem[cur] + 8192;

    // ---- S^T: 2 tiles x 4 mfma32; lane's D = P[px][sigma-slots] ----
    f32x16 s[2];
#pragma unroll
    for (int st = 0; st < 2; ++st) {
      f32x16 z;
#pragma unroll
      for (int r = 0; r < 16; ++r) z[r] = 0.f;
      const unsigned char* krow = sK + (((st << 5) + m) << 7);
#pragma unroll
      for (int ko = 0; ko < 4; ++ko) {
        bf16x8 ka = *(const bf16x8*)(krow + 16 * (((ko << 1) + u2) ^ m7));
        z = MFMA32(ka, qa[ko], z);
      }
      s[st] = z;
    }
    // ---- softmax over 32 in-lane values + 1 shfl (lane^32 = same px) ----
    float tmx[8];
#pragma unroll
    for (int i = 0; i < 8; ++i)
      tmx[i] = fmaxf(fmaxf(s[0][i], s[0][i + 8]), fmaxf(s[1][i], s[1][i + 8]));
    float tm = fmaxf(fmaxf(fmaxf(tmx[0], tmx[1]), fmaxf(tmx[2], tmx[3])),
                     fmaxf(fmaxf(tmx[4], tmx[5]), fmaxf(tmx[6], tmx[7])));
    tm = fmaxf(tm, __shfl_xor(tm, 32));
    float mn = fmaxf(m_, tm);
    if (mn - m_ <= 11.54f) mn = m_;  // defer: P bounded by 2^11.54 = e^8
    float sc = exp2f(m_ - mn);       // exactly 1.0 when deferred
    m_ = mn;
#pragma unroll
    for (int st = 0; st < 2; ++st)
#pragma unroll
      for (int r = 0; r < 16; ++r) s[st][r] = exp2f(s[st][r] - m_);
    float tsx[8];
#pragma unroll
    for (int i = 0; i < 8; ++i)
      tsx[i] = (s[0][i] + s[0][i + 8]) + (s[1][i] + s[1][i + 8]);
    float rs = ((tsx[0] + tsx[1]) + (tsx[2] + tsx[3])) +
               ((tsx[4] + tsx[5]) + (tsx[6] + tsx[7]));
    rs += __shfl_xor(rs, 32);
    l_ = l_ * sc + rs;
    if (__any(sc != 1.f)) {
#pragma unroll
      for (int i = 0; i < 8; ++i)
#pragma unroll
        for (int r = 0; r < 16; ++r) acc[i][r] *= sc;
    }
    // ---- P -> bf16 B-frags, fully in-lane (sigma payoff) ----
    bf16x8 pb[4];
#pragma unroll
    for (int st = 0; st < 2; ++st)
#pragma unroll
      for (int j = 0; j < 8; ++j) {
        pb[2 * st][j] = (bf16)s[st][j];
        pb[2 * st + 1][j] = (bf16)s[st][8 + j];
      }
    // ---- PV: 8 cb x 4 kb mfma32, V A-frags from swizzled LDS ----
#pragma unroll
    for (int cb = 0; cb < 8; ++cb) {
      const unsigned char* vrow = sV + (((cb << 5) + m) << 7);
#pragma unroll
      for (int kb = 0; kb < 4; ++kb) {
        bf16x8 va = *(const bf16x8*)(vrow + 16 * (((kb << 1) + u2) ^ m7));
        acc[cb] = MFMA32(va, pb[kb], acc[cb]);
      }
    }
    if (kt < 15) {
      asm volatile("s_waitcnt vmcnt(0)" ::: "memory");
      __syncthreads();  // next tile landed; everyone done reading cur
      cur ^= 1;
    }
  }

  // ---- epilogue: per-lane normalize, direct stores (32-lane 128B runs) ----
  const float inv = 1.f / l_;
  float* ob = out + ((size_t)b << 18) + px;
#pragma unroll
  for (int cb = 0; cb < 8; ++cb)
#pragma unroll
    for (int r = 0; r < 16; ++r) {
      int c = (cb << 5) + (r & 3) + ((r >> 2) << 3) + (u2 << 2);
      ob[(size_t)c << 10] = acc[cb][r] * inv;
    }
}

// ---------------------------------------------------------------------------
extern "C" void kernel_launch(void* const* d_in, const int* in_sizes, int n_in,
                              void* d_out, int out_size, void* d_ws, size_t ws_size,
                              hipStream_t stream) {
  const float* qf = (const float*)d_in[0];
  const float* kf = (const float*)d_in[1];
  const float* Wq = (const float*)d_in[2];
  const float* bq = (const float*)d_in[3];
  const float* Wk = (const float*)d_in[4];
  const float* bk = (const float*)d_in[5];
  // d_in[6] = vis_CA (unused)
  const int* flag = (const int*)d_in[7];  // same_WqWk
  float* out = (float*)d_out;

  char* ws = (char*)d_ws;
  bf16* Qp = (bf16*)ws;                          // 4 MiB: [32][1024][64] bf16
  bf16* Wbh = (bf16*)(ws + (4u << 20));          // 64 KiB
  bf16* Wbl = (bf16*)(ws + (4u << 20) + 65536);  // 64 KiB
  bf16* KV = (bf16*)(ws + (5u << 20));           // 20 MiB: [32][16] x 40960B chunks

  vprep_kernel<<<4128, 256, 0, stream>>>(kf, Wq, Wk, flag, KV, Wbh, Wbl);
  proj_kernel<<<dim3(8, 32, 2), 256, 0, stream>>>(qf, Wbh, Wbl, bq, bk, flag, Qp, KV);
  attn_kernel<<<512, 128, 0, stream>>>(KV, Qp, out);
}